// Round 1
// baseline (389.033 us; speedup 1.0000x reference)
//
#include <hip/hip_runtime.h>
#include <hip/hip_fp16.h>
#include <cstddef>

#define N_ 1024
#define M_ 1024
#define D_ 1024
#define G_ 16
#define DG_ 64

// ---------------------------------------------------------------------------
// GEMM: C[i][j] = sum_d A[i][d] * Bsel(d,j) + bias[j]
//   BT=false: Bsel = B[d*D_ + j]   (B is D x D row-major)
//   BT=true : Bsel = B[j*D_ + d]   (B is J x D row-major; C = A * B^T)
// 64x64 tile, k-slice 16, 256 threads, 4x4 micro-tile. fp32 baseline.
// ---------------------------------------------------------------------------
template<bool BT>
__global__ __launch_bounds__(256)
void gemm64(const float* __restrict__ A, const float* __restrict__ B,
            const float* __restrict__ bias, float* __restrict__ C)
{
    __shared__ float As[16][68];   // As[k][i], stride 68 = 4*17: float4-aligned, conflict-free
    __shared__ float Bs[16][68];   // Bs[k][j]
    const int tid = threadIdx.x;
    const int tx = tid & 15, ty = tid >> 4;
    const int i0 = blockIdx.x * 64, j0 = blockIdx.y * 64;
    float acc[4][4] = {};

    for (int k0 = 0; k0 < D_; k0 += 16) {
        {
            const int r  = tid >> 2;          // 0..63
            const int kc = (tid & 3) * 4;     // k chunk
            float4 a = *(const float4*)&A[(size_t)(i0 + r) * D_ + k0 + kc];
            As[kc + 0][r] = a.x; As[kc + 1][r] = a.y;
            As[kc + 2][r] = a.z; As[kc + 3][r] = a.w;
            if (BT) {
                float4 b = *(const float4*)&B[(size_t)(j0 + r) * D_ + k0 + kc];
                Bs[kc + 0][r] = b.x; Bs[kc + 1][r] = b.y;
                Bs[kc + 2][r] = b.z; Bs[kc + 3][r] = b.w;
            } else {
                const int kk = tid >> 4, jc = (tid & 15) * 4;
                *(float4*)&Bs[kk][jc] = *(const float4*)&B[(size_t)(k0 + kk) * D_ + j0 + jc];
            }
        }
        __syncthreads();
        #pragma unroll
        for (int k = 0; k < 16; ++k) {
            float4 a4 = *(const float4*)&As[k][ty * 4];
            float4 b4 = *(const float4*)&Bs[k][tx * 4];
            float av[4] = {a4.x, a4.y, a4.z, a4.w};
            float bw[4] = {b4.x, b4.y, b4.z, b4.w};
            #pragma unroll
            for (int i = 0; i < 4; ++i)
                #pragma unroll
                for (int j = 0; j < 4; ++j)
                    acc[i][j] = fmaf(av[i], bw[j], acc[i][j]);
        }
        __syncthreads();
    }

    float4 bb = make_float4(0.f, 0.f, 0.f, 0.f);
    if (bias) bb = *(const float4*)&bias[j0 + tx * 4];
    #pragma unroll
    for (int i = 0; i < 4; ++i) {
        float4 o;
        o.x = acc[i][0] + bb.x; o.y = acc[i][1] + bb.y;
        o.z = acc[i][2] + bb.z; o.w = acc[i][3] + bb.w;
        *(float4*)&C[(size_t)(i0 + ty * 4 + i) * D_ + j0 + tx * 4] = o;
    }
}

// ---------------------------------------------------------------------------
// Positional bias: for each pair (n,m) compute 4 geometric features,
// 8-frequency sin/cos embedding (64 values), contract with Wg (16x64),
// store pbias[g][n][m] = log(relu(. + bg) + 1e-6) as fp16.
// Wg/bg indices are wave-uniform unrolled constants -> expect s_load.
// ---------------------------------------------------------------------------
__global__ __launch_bounds__(256)
void posbias_kernel(const float* __restrict__ rois1, const float* __restrict__ rois2,
                    const float* __restrict__ Wg, const float* __restrict__ bg,
                    __half* __restrict__ pbias)
{
    const int m = blockIdx.x * 256 + threadIdx.x;   // 0..1023
    const int n = blockIdx.y;                       // 0..1023

    const float xmin = rois1[n * 4 + 0], ymin = rois1[n * 4 + 1];
    const float xmax = rois1[n * 4 + 2], ymax = rois1[n * 4 + 3];
    const float w  = xmax - xmin + 1.f, h  = ymax - ymin + 1.f;
    const float cx = 0.5f * (xmin + xmax), cy = 0.5f * (ymin + ymax);

    float4 r2 = *(const float4*)&rois2[m * 4];
    const float wr  = r2.z - r2.x + 1.f, hr  = r2.w - r2.y + 1.f;
    const float cxr = 0.5f * (r2.x + r2.z), cyr = 0.5f * (r2.y + r2.w);

    float feats[4];
    feats[0] = __logf(fabsf((cx - cxr) / w) + 0.001f);
    feats[1] = __logf(fabsf((cy - cyr) / h) + 0.001f);
    feats[2] = __logf(w / wr);
    feats[3] = __logf(h / hr);

    // 100 / 1000^(j/8) = 10^(2 - 3j/8)
    const float fr8[8] = {100.0f, 42.16965f, 17.782794f, 7.4989421f,
                          3.1622777f, 1.3335214f, 0.56234133f, 0.23713737f};

    float acc[G_];
    #pragma unroll
    for (int g = 0; g < G_; ++g) acc[g] = bg[g];

    #pragma unroll
    for (int f = 0; f < 4; ++f) {
        #pragma unroll
        for (int j = 0; j < 8; ++j) {
            const float t  = feats[f] * fr8[j];
            const float sv = __sinf(t);
            const float cv = __cosf(t);
            #pragma unroll
            for (int g = 0; g < G_; ++g) {
                acc[g] = fmaf(sv, Wg[g * 64 + f * 16 + j],
                         fmaf(cv, Wg[g * 64 + f * 16 + 8 + j], acc[g]));
            }
        }
    }

    const size_t base = (size_t)n * M_ + m;
    #pragma unroll
    for (int g = 0; g < G_; ++g) {
        const float v = fmaxf(acc[g], 0.f) + 1e-6f;
        pbias[(size_t)g * N_ * M_ + base] = __float2half(__logf(v));
    }
}

// ---------------------------------------------------------------------------
// Flash attention: block = (n-tile of 64, one group g). 16 m-tiles of 64.
// S = (q*0.125) k^T + pbias ; online softmax over m ; acc += P V.
// Threads 16x16, 4x4 micro-tiles; q/k stored transposed in LDS so both
// GEMM phases read float4 (ds_read_b128) only.
// ---------------------------------------------------------------------------
__global__ __launch_bounds__(256)
void attn_kernel(const float* __restrict__ q, const float* __restrict__ k,
                 const float* __restrict__ V, const __half* __restrict__ pbias,
                 const float* __restrict__ bv, float* __restrict__ out)
{
    __shared__ float qsT[64][68];   // [o][r]  q*0.125 transposed
    __shared__ float ksT[64][68];   // [o][c]  k transposed
    __shared__ float vs[64][68];    // [c][o]  V row-major
    __shared__ float psT[64][68];   // [c][r]  P transposed

    const int tid = threadIdx.x;
    const int tx = tid & 15, ty = tid >> 4;
    const int n0 = blockIdx.x * 64;
    const int g  = blockIdx.y;
    const int r0 = ty * 4, c0 = tx * 4;

    // stage q tile (transposed, pre-scaled by 1/sqrt(DG)=0.125)
    #pragma unroll
    for (int u = 0; u < 4; ++u) {
        int idx = tid + 256 * u;
        int r = idx >> 4;
        int oc = (idx & 15) * 4;
        float4 a = *(const float4*)&q[(size_t)(n0 + r) * D_ + g * DG_ + oc];
        qsT[oc + 0][r] = a.x * 0.125f; qsT[oc + 1][r] = a.y * 0.125f;
        qsT[oc + 2][r] = a.z * 0.125f; qsT[oc + 3][r] = a.w * 0.125f;
    }

    float acc[4][4] = {};
    float mrow[4] = {-1e30f, -1e30f, -1e30f, -1e30f};
    float lrow[4] = {0.f, 0.f, 0.f, 0.f};

    for (int mt = 0; mt < M_ / 64; ++mt) {
        const int m0 = mt * 64;
        __syncthreads();   // prior-iter readers of ksT/vs done (also covers qsT at mt=0)
        #pragma unroll
        for (int u = 0; u < 4; ++u) {
            int idx = tid + 256 * u;
            int c = idx >> 4;
            int oc = (idx & 15) * 4;
            float4 a = *(const float4*)&k[(size_t)(m0 + c) * D_ + g * DG_ + oc];
            ksT[oc + 0][c] = a.x; ksT[oc + 1][c] = a.y;
            ksT[oc + 2][c] = a.z; ksT[oc + 3][c] = a.w;
            float4 b = *(const float4*)&V[(size_t)(m0 + c) * D_ + g * DG_ + oc];
            *(float4*)&vs[c][oc] = b;
        }
        __syncthreads();

        // ---- S = (q/8) k^T + pbias ----
        float s[4][4];
        #pragma unroll
        for (int i = 0; i < 4; ++i) {
            const __half* pp = pbias + ((size_t)g * N_ + n0 + r0 + i) * M_ + m0 + c0;
            __half2 h01 = *(const __half2*)pp;
            __half2 h23 = *(const __half2*)(pp + 2);
            s[i][0] = __low2float(h01); s[i][1] = __high2float(h01);
            s[i][2] = __low2float(h23); s[i][3] = __high2float(h23);
        }
        #pragma unroll 8
        for (int o = 0; o < 64; ++o) {
            float4 a4 = *(const float4*)&qsT[o][r0];
            float4 b4 = *(const float4*)&ksT[o][c0];
            float av[4] = {a4.x, a4.y, a4.z, a4.w};
            float bw[4] = {b4.x, b4.y, b4.z, b4.w};
            #pragma unroll
            for (int i = 0; i < 4; ++i)
                #pragma unroll
                for (int j = 0; j < 4; ++j)
                    s[i][j] = fmaf(av[i], bw[j], s[i][j]);
        }

        // ---- online softmax (rows r0..r0+3, reduce across the 16 tx lanes) ----
        float p[4][4];
        #pragma unroll
        for (int i = 0; i < 4; ++i) {
            float lm = fmaxf(fmaxf(s[i][0], s[i][1]), fmaxf(s[i][2], s[i][3]));
            #pragma unroll
            for (int d = 1; d < 16; d <<= 1)
                lm = fmaxf(lm, __shfl_xor(lm, d, 64));
            const float mnew  = fmaxf(mrow[i], lm);
            const float alpha = __expf(mrow[i] - mnew);
            float rs = 0.f;
            #pragma unroll
            for (int j = 0; j < 4; ++j) { p[i][j] = __expf(s[i][j] - mnew); rs += p[i][j]; }
            #pragma unroll
            for (int d = 1; d < 16; d <<= 1)
                rs += __shfl_xor(rs, d, 64);
            lrow[i] = lrow[i] * alpha + rs;
            mrow[i] = mnew;
            #pragma unroll
            for (int j = 0; j < 4; ++j) acc[i][j] *= alpha;
        }
        #pragma unroll
        for (int j = 0; j < 4; ++j)
            *(float4*)&psT[c0 + j][r0] = make_float4(p[0][j], p[1][j], p[2][j], p[3][j]);
        __syncthreads();

        // ---- acc += P V ----
        #pragma unroll 8
        for (int c = 0; c < 64; ++c) {
            float4 p4 = *(const float4*)&psT[c][r0];
            float4 v4 = *(const float4*)&vs[c][c0];
            float pv[4] = {p4.x, p4.y, p4.z, p4.w};
            float vv[4] = {v4.x, v4.y, v4.z, v4.w};
            #pragma unroll
            for (int i = 0; i < 4; ++i)
                #pragma unroll
                for (int j = 0; j < 4; ++j)
                    acc[i][j] = fmaf(pv[i], vv[j], acc[i][j]);
        }
    }

    // epilogue: normalize, add bv
    #pragma unroll
    for (int i = 0; i < 4; ++i) {
        const float inv = 1.f / lrow[i];
        float4 o;
        o.x = acc[i][0] * inv + bv[g * DG_ + c0 + 0];
        o.y = acc[i][1] * inv + bv[g * DG_ + c0 + 1];
        o.z = acc[i][2] * inv + bv[g * DG_ + c0 + 2];
        o.w = acc[i][3] * inv + bv[g * DG_ + c0 + 3];
        *(float4*)&out[(size_t)(n0 + r0 + i) * D_ + g * DG_ + c0] = o;
    }
}

extern "C" void kernel_launch(void* const* d_in, const int* in_sizes, int n_in,
                              void* d_out, int out_size, void* d_ws, size_t ws_size,
                              hipStream_t stream) {
    const float* roi_feat = (const float*)d_in[0];
    const float* ref_feat = (const float*)d_in[1];
    const float* rois1    = (const float*)d_in[2];
    const float* rois2    = (const float*)d_in[3];
    const float* Wq       = (const float*)d_in[4];
    const float* bq       = (const float*)d_in[5];
    const float* Wk       = (const float*)d_in[6];
    const float* bk       = (const float*)d_in[7];
    const float* Wg       = (const float*)d_in[8];
    const float* bg       = (const float*)d_in[9];
    const float* Wv       = (const float*)d_in[10];
    const float* bv       = (const float*)d_in[11];
    float* out = (float*)d_out;

    // ws layout (floats): q[1M] | k[1M] | V[1M] | pbias as fp16 (16M halves = 32MB)
    float* wsf   = (float*)d_ws;
    float* qbuf  = wsf;
    float* kbuf  = wsf + (1u << 20);
    float* Vbuf  = wsf + (2u << 20);
    __half* pbias = (__half*)(wsf + 3u * (1u << 20));

    dim3 blk(256);
    gemm64<false><<<dim3(16, 16), blk, 0, stream>>>(roi_feat, Wq, bq, qbuf);
    gemm64<false><<<dim3(16, 16), blk, 0, stream>>>(ref_feat, Wk, bk, kbuf);
    gemm64<true ><<<dim3(16, 16), blk, 0, stream>>>(ref_feat, Wv, nullptr, Vbuf);
    posbias_kernel<<<dim3(4, 1024), blk, 0, stream>>>(rois1, rois2, Wg, bg, pbias);
    attn_kernel<<<dim3(16, 16), blk, 0, stream>>>(qbuf, kbuf, Vbuf, pbias, bv, out);
}

// Round 2
// 186.187 us; speedup vs baseline: 2.0895x; 2.0895x over previous
//
#include <hip/hip_runtime.h>
#include <hip/hip_fp16.h>
#include <cstddef>

#define N_ 1024
#define M_ 1024
#define D_ 1024
#define G_ 16
#define DG_ 64

typedef __bf16 bf16x8 __attribute__((ext_vector_type(8)));
typedef float f32x4 __attribute__((ext_vector_type(4)));

// ---------------------------------------------------------------------------
// Transpose-cast: WqT/WkT[j][d] = (bf16) W[d][j].  64x64 tiles.
// ---------------------------------------------------------------------------
__global__ __launch_bounds__(256)
void transpose_cast(const float* __restrict__ Wq, const float* __restrict__ Wk,
                    __bf16* __restrict__ WqT, __bf16* __restrict__ WkT)
{
    __shared__ float t[64][65];
    const float* src = blockIdx.z ? Wk : Wq;
    __bf16* dst = blockIdx.z ? WkT : WqT;
    const int i0 = blockIdx.x * 64, j0 = blockIdx.y * 64;
    const int tid = threadIdx.x;
    const int r = tid >> 4, c4 = (tid & 15) * 4;
    #pragma unroll
    for (int it = 0; it < 4; ++it) {
        float4 a = *(const float4*)&src[(size_t)(i0 + r + it * 16) * D_ + j0 + c4];
        t[r + it * 16][c4 + 0] = a.x; t[r + it * 16][c4 + 1] = a.y;
        t[r + it * 16][c4 + 2] = a.z; t[r + it * 16][c4 + 3] = a.w;
    }
    __syncthreads();
    #pragma unroll
    for (int it = 0; it < 4; ++it) {
        const int row = r + it * 16;   // j within tile
        __bf16 p[4];
        #pragma unroll
        for (int q = 0; q < 4; ++q) p[q] = (__bf16)t[c4 + q][row];
        *(uint2*)&dst[(size_t)(j0 + row) * D_ + i0 + c4] = *(const uint2*)p;
    }
}

// Plain cast for Wv (already [go][d] = B^T layout).
__global__ __launch_bounds__(256)
void cast_wv(const float* __restrict__ Wv, __bf16* __restrict__ out)
{
    const int idx = blockIdx.x * 256 + threadIdx.x;
    float4 a = *(const float4*)&Wv[(size_t)idx * 4];
    __bf16 p[4] = {(__bf16)a.x, (__bf16)a.y, (__bf16)a.z, (__bf16)a.w};
    *(uint2*)&out[(size_t)idx * 4] = *(const uint2*)p;
}

// ---------------------------------------------------------------------------
// Fused MFMA GEMM, 128x128 tile, BK=64, 4 waves of 64x64 (4x4 MFMA tiles).
// z=0: q_bf[n][go] = bf16((roi@Wq + bq)*0.125)
// z=1: k_bf[m][go] = bf16(ref@Wk + bk)
// z=2: Vt_bf[go][m] = bf16(ref@Wv^T)   (stored transposed)
// A is fp32 (cast to bf16 during LDS staging); B is pre-cast bf16 [n_out][k].
// ---------------------------------------------------------------------------
__global__ __launch_bounds__(256)
void gemm_mfma(const float* __restrict__ roi, const float* __restrict__ ref,
               const __bf16* __restrict__ WqT, const __bf16* __restrict__ WkT,
               const __bf16* __restrict__ Wvb,
               const float* __restrict__ bq, const float* __restrict__ bk,
               __bf16* __restrict__ qout, __bf16* __restrict__ kout,
               __bf16* __restrict__ Vt)
{
    __shared__ __bf16 As[128][72];
    __shared__ __bf16 Bs[128][72];
    const int z = blockIdx.z;
    const float* A = (z == 0) ? roi : ref;
    const __bf16* B = (z == 0) ? WqT : (z == 1) ? WkT : Wvb;
    const int tid = threadIdx.x;
    const int i0 = blockIdx.x * 128, j0 = blockIdx.y * 128;
    const int w = tid >> 6, lane = tid & 63;
    const int quad = lane >> 4, l15 = lane & 15;
    const int iw = (w & 1) * 64, jw = (w >> 1) * 64;

    f32x4 acc[4][4] = {};

    for (int k0 = 0; k0 < D_; k0 += 64) {
        __syncthreads();
        #pragma unroll
        for (int it = 0; it < 8; ++it) {       // A: 128 rows x 16 float4 chunks
            const int idx = tid + 256 * it;
            const int row = idx >> 4, c = idx & 15;
            float4 a = *(const float4*)&A[(size_t)(i0 + row) * D_ + k0 + c * 4];
            __bf16* d = &As[row][c * 4];
            d[0] = (__bf16)a.x; d[1] = (__bf16)a.y; d[2] = (__bf16)a.z; d[3] = (__bf16)a.w;
        }
        #pragma unroll
        for (int it = 0; it < 4; ++it) {       // B: 128 rows x 8 x (8 bf16) chunks
            const int idx = tid + 256 * it;
            const int row = idx >> 3, c = idx & 7;
            *(uint4*)&Bs[row][c * 8] = *(const uint4*)&B[(size_t)(j0 + row) * D_ + k0 + c * 8];
        }
        __syncthreads();
        #pragma unroll
        for (int ks = 0; ks < 2; ++ks) {
            bf16x8 af[4], bf[4];
            #pragma unroll
            for (int t = 0; t < 4; ++t) {
                af[t] = *(const bf16x8*)&As[iw + t * 16 + l15][ks * 32 + quad * 8];
                bf[t] = *(const bf16x8*)&Bs[jw + t * 16 + l15][ks * 32 + quad * 8];
            }
            #pragma unroll
            for (int ti = 0; ti < 4; ++ti)
                #pragma unroll
                for (int tj = 0; tj < 4; ++tj)
                    acc[ti][tj] = __builtin_amdgcn_mfma_f32_16x16x32_bf16(
                        af[ti], bf[tj], acc[ti][tj], 0, 0, 0);
        }
    }

    if (z < 2) {
        const float* bias = (z == 0) ? bq : bk;
        __bf16* out = (z == 0) ? qout : kout;
        const float scale = (z == 0) ? 0.125f : 1.0f;
        #pragma unroll
        for (int ti = 0; ti < 4; ++ti)
            #pragma unroll
            for (int tj = 0; tj < 4; ++tj) {
                const int col = j0 + jw + tj * 16 + l15;
                const float bb = bias[col];
                #pragma unroll
                for (int r = 0; r < 4; ++r) {
                    const int rowi = i0 + iw + ti * 16 + quad * 4 + r;
                    out[(size_t)rowi * D_ + col] = (__bf16)((acc[ti][tj][r] + bb) * scale);
                }
            }
    } else {
        #pragma unroll
        for (int ti = 0; ti < 4; ++ti)
            #pragma unroll
            for (int tj = 0; tj < 4; ++tj) {
                const int col = j0 + jw + tj * 16 + l15;        // go
                const int row0 = i0 + iw + ti * 16 + quad * 4;  // m base (4 consecutive)
                __bf16 p[4];
                #pragma unroll
                for (int r = 0; r < 4; ++r) p[r] = (__bf16)acc[ti][tj][r];
                *(uint2*)&Vt[(size_t)col * M_ + row0] = *(const uint2*)p;
            }
    }
}

// ---------------------------------------------------------------------------
// Positional affinity weight (no log — softmax identity moves it into attn):
// aw[g][n][m] = fp16( relu(emb(n,m)·Wg[g] + bg[g]) + 1e-6 )
// ---------------------------------------------------------------------------
__global__ __launch_bounds__(256)
void posbias_kernel(const float* __restrict__ rois1, const float* __restrict__ rois2,
                    const float* __restrict__ Wg, const float* __restrict__ bg,
                    __half* __restrict__ aw)
{
    const int m = blockIdx.x * 256 + threadIdx.x;
    const int n = blockIdx.y;

    const float xmin = rois1[n * 4 + 0], ymin = rois1[n * 4 + 1];
    const float xmax = rois1[n * 4 + 2], ymax = rois1[n * 4 + 3];
    const float w  = xmax - xmin + 1.f, h  = ymax - ymin + 1.f;
    const float cx = 0.5f * (xmin + xmax), cy = 0.5f * (ymin + ymax);

    float4 r2 = *(const float4*)&rois2[m * 4];
    const float wr  = r2.z - r2.x + 1.f, hr  = r2.w - r2.y + 1.f;
    const float cxr = 0.5f * (r2.x + r2.z), cyr = 0.5f * (r2.y + r2.w);

    float feats[4];
    feats[0] = __logf(fabsf((cx - cxr) / w) + 0.001f);
    feats[1] = __logf(fabsf((cy - cyr) / h) + 0.001f);
    feats[2] = __logf(w / wr);
    feats[3] = __logf(h / hr);

    const float fr8[8] = {100.0f, 42.16965f, 17.782794f, 7.4989421f,
                          3.1622777f, 1.3335214f, 0.56234133f, 0.23713737f};

    float acc[G_];
    #pragma unroll
    for (int g = 0; g < G_; ++g) acc[g] = bg[g];

    #pragma unroll
    for (int f = 0; f < 4; ++f) {
        #pragma unroll
        for (int j = 0; j < 8; ++j) {
            const float t  = feats[f] * fr8[j];
            const float sv = __sinf(t);
            const float cv = __cosf(t);
            #pragma unroll
            for (int g = 0; g < G_; ++g) {
                acc[g] = fmaf(sv, Wg[g * 64 + f * 16 + j],
                         fmaf(cv, Wg[g * 64 + f * 16 + 8 + j], acc[g]));
            }
        }
    }

    const size_t base = (size_t)n * M_ + m;
    #pragma unroll
    for (int g = 0; g < G_; ++g)
        aw[(size_t)g * N_ * M_ + base] = __float2half(fmaxf(acc[g], 0.f) + 1e-6f);
}

// ---------------------------------------------------------------------------
// MFMA flash attention. Block = (64-row n-tile, group g); 4 waves, each wave
// owns 16 n-rows. P = aw * exp(s - mrow); out = (P·V)/l + bv.
// ---------------------------------------------------------------------------
__global__ __launch_bounds__(256)
void attn_mfma(const __bf16* __restrict__ qb, const __bf16* __restrict__ kb,
               const __bf16* __restrict__ Vt, const __half* __restrict__ aw,
               const float* __restrict__ bv, float* __restrict__ out)
{
    __shared__ __bf16 qs[64][72];
    __shared__ __bf16 Ks[64][72];
    __shared__ __bf16 Vs[64][72];   // [o][m]
    __shared__ __bf16 Ps[64][72];   // [n][m] (wave-private row bands)
    __shared__ __half AWs[64][72];

    const int tid = threadIdx.x;
    const int w = tid >> 6, lane = tid & 63;
    const int quad = lane >> 4, l15 = lane & 15;
    const int n0 = blockIdx.x * 64, g = blockIdx.y;

    #pragma unroll
    for (int it = 0; it < 2; ++it) {
        const int idx = tid + 256 * it;
        const int row = idx >> 3, c = idx & 7;
        *(uint4*)&qs[row][c * 8] = *(const uint4*)&qb[(size_t)(n0 + row) * D_ + g * 64 + c * 8];
    }

    f32x4 acc[4] = {};
    float mrow[4], lrow[4];
    #pragma unroll
    for (int r = 0; r < 4; ++r) { mrow[r] = -1e30f; lrow[r] = 0.f; }

    for (int mt = 0; mt < 16; ++mt) {
        const int m0 = mt * 64;
        __syncthreads();
        #pragma unroll
        for (int it = 0; it < 2; ++it) {
            const int idx = tid + 256 * it;
            const int row = idx >> 3, c = idx & 7;
            *(uint4*)&Ks[row][c * 8]  = *(const uint4*)&kb[(size_t)(m0 + row) * D_ + g * 64 + c * 8];
            *(uint4*)&Vs[row][c * 8]  = *(const uint4*)&Vt[(size_t)(g * 64 + row) * M_ + m0 + c * 8];
            *(uint4*)&AWs[row][c * 8] = *(const uint4*)&aw[((size_t)g * N_ + n0 + row) * M_ + m0 + c * 8];
        }
        __syncthreads();

        // S = q k^T : wave rows w*16.., 4 column tiles of m
        f32x4 s[4] = {};
        #pragma unroll
        for (int ks = 0; ks < 2; ++ks) {
            bf16x8 a = *(const bf16x8*)&qs[w * 16 + l15][ks * 32 + quad * 8];
            #pragma unroll
            for (int t = 0; t < 4; ++t) {
                bf16x8 b = *(const bf16x8*)&Ks[t * 16 + l15][ks * 32 + quad * 8];
                s[t] = __builtin_amdgcn_mfma_f32_16x16x32_bf16(a, b, s[t], 0, 0, 0);
            }
        }

        // online softmax per row (n = w*16 + quad*4 + r), reduce over low-4 lane bits
        #pragma unroll
        for (int r = 0; r < 4; ++r) {
            float vm = fmaxf(fmaxf(s[0][r], s[1][r]), fmaxf(s[2][r], s[3][r]));
            #pragma unroll
            for (int d = 1; d < 16; d <<= 1) vm = fmaxf(vm, __shfl_xor(vm, d, 64));
            const float mnew  = fmaxf(mrow[r], vm);
            const float alpha = __expf(mrow[r] - mnew);
            mrow[r] = mnew;
            const int nrow = w * 16 + quad * 4 + r;
            float rs = 0.f;
            #pragma unroll
            for (int t = 0; t < 4; ++t) {
                const float e = __expf(s[t][r] - mnew);
                const float p = __half2float(AWs[nrow][t * 16 + l15]) * e;
                rs += p;
                Ps[nrow][t * 16 + l15] = (__bf16)p;
            }
            #pragma unroll
            for (int d = 1; d < 16; d <<= 1) rs += __shfl_xor(rs, d, 64);
            lrow[r] = lrow[r] * alpha + rs;
            #pragma unroll
            for (int t = 0; t < 4; ++t) acc[t][r] *= alpha;
        }

        // acc += P V   (A = Ps wave-private rows; B = Vs[o][m])
        #pragma unroll
        for (int ks = 0; ks < 2; ++ks) {
            bf16x8 a = *(const bf16x8*)&Ps[w * 16 + l15][ks * 32 + quad * 8];
            #pragma unroll
            for (int t = 0; t < 4; ++t) {
                bf16x8 b = *(const bf16x8*)&Vs[t * 16 + l15][ks * 32 + quad * 8];
                acc[t] = __builtin_amdgcn_mfma_f32_16x16x32_bf16(a, b, acc[t], 0, 0, 0);
            }
        }
    }

    #pragma unroll
    for (int r = 0; r < 4; ++r) {
        const float inv = 1.f / lrow[r];
        const int nrow = n0 + w * 16 + quad * 4 + r;
        #pragma unroll
        for (int t = 0; t < 4; ++t) {
            const int col = g * 64 + t * 16 + l15;
            out[(size_t)nrow * D_ + col] = acc[t][r] * inv + bv[col];
        }
    }
}

extern "C" void kernel_launch(void* const* d_in, const int* in_sizes, int n_in,
                              void* d_out, int out_size, void* d_ws, size_t ws_size,
                              hipStream_t stream) {
    const float* roi_feat = (const float*)d_in[0];
    const float* ref_feat = (const float*)d_in[1];
    const float* rois1    = (const float*)d_in[2];
    const float* rois2    = (const float*)d_in[3];
    const float* Wq       = (const float*)d_in[4];
    const float* bq       = (const float*)d_in[5];
    const float* Wk       = (const float*)d_in[6];
    const float* bk       = (const float*)d_in[7];
    const float* Wg       = (const float*)d_in[8];
    const float* bg       = (const float*)d_in[9];
    const float* Wv       = (const float*)d_in[10];
    const float* bv       = (const float*)d_in[11];
    float* out = (float*)d_out;

    // ws layout (bytes): WqT 0..2M | WkT 2..4M | Wv_bf 4..6M | q 6..8M |
    //                    k 8..10M | Vt 10..12M | aw 12..44M (fp16)
    char* ws = (char*)d_ws;
    __bf16* WqT  = (__bf16*)(ws + 0);
    __bf16* WkT  = (__bf16*)(ws + (2u << 20));
    __bf16* Wvb  = (__bf16*)(ws + (4u << 20));
    __bf16* qbuf = (__bf16*)(ws + (6u << 20));
    __bf16* kbuf = (__bf16*)(ws + (8u << 20));
    __bf16* Vtb  = (__bf16*)(ws + (10u << 20));
    __half* aw   = (__half*)(ws + (12u << 20));

    dim3 blk(256);
    transpose_cast<<<dim3(16, 16, 2), blk, 0, stream>>>(Wq, Wk, WqT, WkT);
    cast_wv<<<dim3(1024), blk, 0, stream>>>(Wv, Wvb);
    posbias_kernel<<<dim3(4, 1024), blk, 0, stream>>>(rois1, rois2, Wg, bg, aw);
    gemm_mfma<<<dim3(8, 8, 3), blk, 0, stream>>>(roi_feat, ref_feat, WqT, WkT, Wvb,
                                                 bq, bk, qbuf, kbuf, Vtb);
    attn_mfma<<<dim3(16, 16), blk, 0, stream>>>(qbuf, kbuf, Vtb, aw, bv, out);
}